// Round 1
// baseline (127.898 us; speedup 1.0000x reference)
//
#include <hip/hip_runtime.h>

// Simplex projection along last dim (n = 12288), rows = 4096, fp32.
// wp = max(x - tau, 0), wc = x - wp, where tau solves sum(max(x-tau,0)) = Z.
// tau found by Michelot's exact fixed-point iteration (no sort needed).

constexpr int   N_COLS = 12288;
constexpr int   BLOCK  = 256;
constexpr int   V4_PER = N_COLS / (BLOCK * 4);   // 12 float4 per thread
constexpr int   PER    = V4_PER * 4;             // 48 scalars per thread
constexpr float Z_LVL  = 1.0f;

__global__ __launch_bounds__(BLOCK) void simplex_proj_kernel(
    const float* __restrict__ x,
    float* __restrict__ wp,
    float* __restrict__ wc) {

  const int    row  = blockIdx.x;
  const size_t base = (size_t)row * N_COLS;
  const float4* __restrict__ xin = reinterpret_cast<const float4*>(x + base);

  // ---- load row chunk into registers (coalesced float4) ----
  float v[PER];
  #pragma unroll
  for (int k = 0; k < V4_PER; ++k) {
    float4 t = xin[threadIdx.x + k * BLOCK];
    v[4 * k + 0] = t.x;
    v[4 * k + 1] = t.y;
    v[4 * k + 2] = t.z;
    v[4 * k + 3] = t.w;
  }

  __shared__ float s_sum[BLOCK / 64];
  __shared__ int   s_cnt[BLOCK / 64];
  __shared__ float s_tau;
  __shared__ int   s_count;

  const int lane = threadIdx.x & 63;
  const int wave = threadIdx.x >> 6;

  float tau        = -3.0e38f;   // first pass: everything active
  int   prev_count = -1;

  for (int iter = 0; iter < 64; ++iter) {
    // partial sum & count of active elements (x > tau)
    float ps = 0.0f;
    int   pc = 0;
    #pragma unroll
    for (int k = 0; k < PER; ++k) {
      if (v[k] > tau) { ps += v[k]; pc += 1; }
    }
    // 64-lane wave reduction
    #pragma unroll
    for (int off = 32; off >= 1; off >>= 1) {
      ps += __shfl_down(ps, off, 64);
      pc += __shfl_down(pc, off, 64);
    }
    if (lane == 0) { s_sum[wave] = ps; s_cnt[wave] = pc; }
    __syncthreads();
    if (threadIdx.x == 0) {
      float tsum = 0.0f;
      int   tcnt = 0;
      #pragma unroll
      for (int w = 0; w < BLOCK / 64; ++w) { tsum += s_sum[w]; tcnt += s_cnt[w]; }
      s_tau   = (tsum - Z_LVL) / (float)tcnt;
      s_count = tcnt;
    }
    __syncthreads();
    tau = s_tau;
    int cnt = s_count;
    if (cnt == prev_count) break;  // active set stable -> tau exact
    prev_count = cnt;
    __syncthreads();  // protect s_sum/s_cnt reuse next iteration
  }

  // ---- write wp / wc (coalesced float4) ----
  float4* __restrict__ wpo = reinterpret_cast<float4*>(wp + base);
  float4* __restrict__ wco = reinterpret_cast<float4*>(wc + base);
  #pragma unroll
  for (int k = 0; k < V4_PER; ++k) {
    float a0 = v[4 * k + 0], a1 = v[4 * k + 1], a2 = v[4 * k + 2], a3 = v[4 * k + 3];
    float p0 = fmaxf(a0 - tau, 0.0f);
    float p1 = fmaxf(a1 - tau, 0.0f);
    float p2 = fmaxf(a2 - tau, 0.0f);
    float p3 = fmaxf(a3 - tau, 0.0f);
    wpo[threadIdx.x + k * BLOCK] = make_float4(p0, p1, p2, p3);
    wco[threadIdx.x + k * BLOCK] = make_float4(a0 - p0, a1 - p1, a2 - p2, a3 - p3);
  }
}

extern "C" void kernel_launch(void* const* d_in, const int* in_sizes, int n_in,
                              void* d_out, int out_size, void* d_ws, size_t ws_size,
                              hipStream_t stream) {
  const float* x = (const float*)d_in[0];
  const int rows = in_sizes[0] / N_COLS;

  float* wp = (float*)d_out;
  float* wc = wp + (size_t)rows * N_COLS;

  simplex_proj_kernel<<<rows, BLOCK, 0, stream>>>(x, wp, wc);
}

// Round 2
// 125.178 us; speedup vs baseline: 1.0217x; 1.0217x over previous
//
#include <hip/hip_runtime.h>

// Simplex projection along last dim (n = 12288), rows = 4096, fp32.
// wp = max(x - tau, 0), wc = x - wp, tau solves sum(max(x-tau,0)) = Z.
// Michelot fixed-point (exact, no sort): tau_{k+1} = (sum_{x>tau_k} x - Z)/|{x>tau_k}|.
// tau is monotone increasing -> active set shrinks monotonically.

constexpr int   N_COLS = 12288;
constexpr int   BLOCK  = 256;
constexpr int   NWAVE  = BLOCK / 64;
constexpr int   V4_PER = N_COLS / (BLOCK * 4);   // 12 float4 per thread
constexpr int   PER    = V4_PER * 4;             // 48 scalars per thread
constexpr float Z_LVL  = 1.0f;
constexpr int   CAP    = 1024;                   // LDS compaction capacity

typedef float f32x4 __attribute__((ext_vector_type(4)));

__device__ __forceinline__ float wave_sum_f(float v) {
#pragma unroll
  for (int off = 32; off >= 1; off >>= 1) v += __shfl_down(v, off, 64);
  return v;
}
__device__ __forceinline__ int wave_sum_i(int v) {
#pragma unroll
  for (int off = 32; off >= 1; off >>= 1) v += __shfl_down(v, off, 64);
  return v;
}

__global__ __launch_bounds__(BLOCK) void simplex_proj_kernel(
    const float* __restrict__ x, float* __restrict__ wp, float* __restrict__ wc) {

  const int    tid  = threadIdx.x;
  const int    lane = tid & 63;
  const int    wave = tid >> 6;
  const size_t base = (size_t)blockIdx.x * N_COLS;
  const f32x4* __restrict__ xin = reinterpret_cast<const f32x4*>(x + base);

  __shared__ float s_sum[2][NWAVE];
  __shared__ int   s_cnt[2][NWAVE];
  __shared__ int   s_wtot[NWAVE];
  __shared__ float s_act[CAP];

  // ---- load row into registers + full-row sum (Michelot iter 0 fused) ----
  float v[PER];
  float part = 0.0f;
#pragma unroll
  for (int k = 0; k < V4_PER; ++k) {
    f32x4 t = __builtin_nontemporal_load(&xin[tid + k * BLOCK]);
    v[4*k+0] = t.x; v[4*k+1] = t.y; v[4*k+2] = t.z; v[4*k+3] = t.w;
    part += (t.x + t.y) + (t.z + t.w);
  }
  part = wave_sum_f(part);
  if (lane == 0) s_sum[0][wave] = part;
  __syncthreads();
  float S0 = 0.f;
#pragma unroll
  for (int w = 0; w < NWAVE; ++w) S0 += s_sum[0][w];
  float tau  = (S0 - Z_LVL) / (float)N_COLS;
  int   prev = N_COLS;

  // ---- register-phase Michelot: count via ballot (SALU), 1 barrier/iter ----
  int nact = -1;  // >=0 once compacted into LDS
  for (int iter = 0; iter < 32; ++iter) {
    const int p = (iter + 1) & 1;
    float ps = 0.f;
    int   pc = 0;  // wave-uniform (SGPR) count
#pragma unroll
    for (int k = 0; k < PER; ++k) {
      bool a = v[k] > tau;
      unsigned long long m = __ballot(a);
      pc += (int)__popcll(m);
      ps += a ? v[k] : 0.f;
    }
    ps = wave_sum_f(ps);
    if (lane == 0) { s_sum[p][wave] = ps; s_cnt[p][wave] = pc; }
    __syncthreads();
    float S = 0.f; int C = 0;
#pragma unroll
    for (int w = 0; w < NWAVE; ++w) { S += s_sum[p][w]; C += s_cnt[p][w]; }
    tau = (S - Z_LVL) / (float)C;     // uniform across block
    if (C == prev) break;             // active set stable -> tau exact
    prev = C;
    if (C <= CAP) {
      // ---- one-time compaction of {v > tau} into LDS ----
      int nt = 0;
#pragma unroll
      for (int k = 0; k < PER; ++k) nt += (v[k] > tau) ? 1 : 0;
      int pre = nt;  // inclusive prefix within wave
#pragma unroll
      for (int off = 1; off < 64; off <<= 1) {
        int t = __shfl_up(pre, off, 64);
        if (lane >= off) pre += t;
      }
      if (lane == 63) s_wtot[wave] = pre;
      const int my = pre - nt;  // exclusive prefix within wave
      __syncthreads();
      int wb = 0, ntot = 0;
#pragma unroll
      for (int w = 0; w < NWAVE; ++w) { if (w < wave) wb += s_wtot[w]; ntot += s_wtot[w]; }
      int o = wb + my;
#pragma unroll
      for (int k = 0; k < PER; ++k) if (v[k] > tau) s_act[o++] = v[k];
      nact = ntot;
      __syncthreads();
      break;
    }
  }

  // ---- LDS-phase Michelot on compacted actives (<=4 elems/thread) ----
  if (nact >= 0) {
    for (int it2 = 0; it2 < 64; ++it2) {
      const int p = it2 & 1;
      float ps = 0.f;
      int   pc = 0;
      for (int i = tid; i < nact; i += BLOCK) {
        float a = s_act[i];
        bool g = a > tau;
        ps += g ? a : 0.f;
        pc += g ? 1 : 0;
      }
      ps = wave_sum_f(ps);
      pc = wave_sum_i(pc);
      if (lane == 0) { s_sum[p][wave] = ps; s_cnt[p][wave] = pc; }
      __syncthreads();
      float S = 0.f; int C = 0;
#pragma unroll
      for (int w = 0; w < NWAVE; ++w) { S += s_sum[p][w]; C += s_cnt[p][w]; }
      tau = (S - Z_LVL) / (float)C;
      if (C == prev) break;
      prev = C;
    }
  }

  // ---- write wp / wc (coalesced float4, nontemporal) ----
  f32x4* __restrict__ wpo = reinterpret_cast<f32x4*>(wp + base);
  f32x4* __restrict__ wco = reinterpret_cast<f32x4*>(wc + base);
#pragma unroll
  for (int k = 0; k < V4_PER; ++k) {
    f32x4 a  = { v[4*k+0], v[4*k+1], v[4*k+2], v[4*k+3] };
    f32x4 pv, cv;
    pv.x = fmaxf(a.x - tau, 0.f);  cv.x = a.x - pv.x;
    pv.y = fmaxf(a.y - tau, 0.f);  cv.y = a.y - pv.y;
    pv.z = fmaxf(a.z - tau, 0.f);  cv.z = a.z - pv.z;
    pv.w = fmaxf(a.w - tau, 0.f);  cv.w = a.w - pv.w;
    __builtin_nontemporal_store(pv, &wpo[tid + k * BLOCK]);
    __builtin_nontemporal_store(cv, &wco[tid + k * BLOCK]);
  }
}

extern "C" void kernel_launch(void* const* d_in, const int* in_sizes, int n_in,
                              void* d_out, int out_size, void* d_ws, size_t ws_size,
                              hipStream_t stream) {
  const float* x = (const float*)d_in[0];
  const int rows = in_sizes[0] / N_COLS;

  float* wp = (float*)d_out;
  float* wc = wp + (size_t)rows * N_COLS;

  simplex_proj_kernel<<<rows, BLOCK, 0, stream>>>(x, wp, wc);
}

// Round 3
// 118.296 us; speedup vs baseline: 1.0812x; 1.0582x over previous
//
#include <hip/hip_runtime.h>

// Simplex projection along last dim (n = 12288), rows = 4096, fp32.
// wp = max(x - tau, 0), wc = x - wp, tau solves sum(max(x-tau,0)) = Z.
//
// Michelot fixed-point: tau_{k+1} = (sum_{x>tau_k} x - Z)/|{x>tau_k}|.
// Valid from ANY start tau <= tau* (then tau_k increases monotonically to tau*,
// and count-stable <=> exact fixed point). We bootstrap tau from threshold
// statistics (Sum_{x>t}, Count_{x>t} for t in {0,1,2,3}) accumulated DURING the
// load (VALU is free under the BW-bound load phase): the largest t with
// g(t) = S_t - t*C_t >= Z satisfies t <= tau*, so {x > t} contains the support.
// For N(0,1) rows t=3 gives ~17 actives -> compact to LDS, solve on one wave.

constexpr int   N_COLS = 12288;
constexpr int   BLOCK  = 256;
constexpr int   NWAVE  = BLOCK / 64;
constexpr int   V4_PER = N_COLS / (BLOCK * 4);   // 12 float4 per thread
constexpr int   PER    = V4_PER * 4;             // 48 scalars per thread
constexpr float Z_LVL  = 1.0f;
constexpr int   CAP    = 1024;                   // LDS compaction capacity
constexpr int   NTHR   = 4;                      // thresholds 0,1,2,3

typedef float f32x4 __attribute__((ext_vector_type(4)));

__device__ __forceinline__ float wave_sum_f(float v) {
#pragma unroll
  for (int off = 32; off >= 1; off >>= 1) v += __shfl_down(v, off, 64);
  return v;
}
__device__ __forceinline__ int wave_sum_i(int v) {
#pragma unroll
  for (int off = 32; off >= 1; off >>= 1) v += __shfl_down(v, off, 64);
  return v;
}
__device__ __forceinline__ float wave_bcast_sum_f(float v) {
#pragma unroll
  for (int off = 32; off >= 1; off >>= 1) v += __shfl_xor(v, off, 64);
  return v;
}

__global__ __launch_bounds__(BLOCK, 4) void simplex_proj_kernel(
    const float* __restrict__ x, float* __restrict__ wp, float* __restrict__ wc) {

  const int    tid  = threadIdx.x;
  const int    lane = tid & 63;
  const int    wave = tid >> 6;
  const size_t base = (size_t)blockIdx.x * N_COLS;
  const f32x4* __restrict__ xin = reinterpret_cast<const f32x4*>(x + base);

  __shared__ float s_f[NWAVE][NTHR + 1];   // [w][0]=full sum, [w][1+q]=S_q
  __shared__ int   s_i[NWAVE][NTHR];       // [w][q]=C_q (per-wave counts)
  __shared__ float s_act[CAP];
  __shared__ float s_tau;
  __shared__ float s_sum2[2][NWAVE];       // fallback parity buffers
  __shared__ int   s_cnt2[2][NWAVE];
  __shared__ int   s_wtot[NWAVE];

  // ---- load row into registers; accumulate threshold stats (free under BW) ----
  float v[PER];
  float sAll = 0.f;
  float sT[NTHR] = {0.f, 0.f, 0.f, 0.f};
  int   cT[NTHR] = {0, 0, 0, 0};
#pragma unroll
  for (int k = 0; k < V4_PER; ++k) {
    f32x4 t = __builtin_nontemporal_load(&xin[tid + k * BLOCK]);
    v[4*k+0] = t.x; v[4*k+1] = t.y; v[4*k+2] = t.z; v[4*k+3] = t.w;
#pragma unroll
    for (int j = 0; j < 4; ++j) {
      float e = v[4*k+j];
      sAll += e;
#pragma unroll
      for (int q = 0; q < NTHR; ++q) {
        bool a = e > (float)q;
        sT[q] += a ? e : 0.f;
        cT[q] += a ? 1 : 0;
      }
    }
  }

  // ---- one-barrier block reduction of all 9 stats ----
  sAll = wave_sum_f(sAll);
#pragma unroll
  for (int q = 0; q < NTHR; ++q) { sT[q] = wave_sum_f(sT[q]); cT[q] = wave_sum_i(cT[q]); }
  if (lane == 0) {
    s_f[wave][0] = sAll;
#pragma unroll
    for (int q = 0; q < NTHR; ++q) { s_f[wave][1 + q] = sT[q]; s_i[wave][q] = cT[q]; }
  }
  __syncthreads();
  float S = 0.f, ST[NTHR] = {0.f, 0.f, 0.f, 0.f};
  int   CT[NTHR] = {0, 0, 0, 0};
#pragma unroll
  for (int w = 0; w < NWAVE; ++w) {
    S += s_f[w][0];
#pragma unroll
    for (int q = 0; q < NTHR; ++q) { ST[q] += s_f[w][1 + q]; CT[q] += s_i[w][q]; }
  }

  // ---- pick largest valid bootstrap threshold ----
  int pickT = -1;
#pragma unroll
  for (int q = NTHR - 1; q >= 0; --q) {
    if (pickT < 0 && CT[q] > 0 && CT[q] <= CAP &&
        (ST[q] - (float)q * (float)CT[q]) >= Z_LVL + 0.01f) pickT = q;
  }

  float tau;
  int   prev;
  int   nact = -1;

  if (pickT >= 0) {
    // ---- fast path: compact {x > pickT} to LDS, start tau from its stats ----
    tau  = (ST[pickT] - Z_LVL) / (float)CT[pickT];
    prev = CT[pickT];
    const float tf = (float)pickT;
    int nt = 0;
#pragma unroll
    for (int k = 0; k < PER; ++k) nt += (v[k] > tf) ? 1 : 0;
    int pre = nt;  // inclusive prefix within wave
#pragma unroll
    for (int off = 1; off < 64; off <<= 1) {
      int t = __shfl_up(pre, off, 64);
      if (lane >= off) pre += t;
    }
    int wb = 0;
#pragma unroll
    for (int w = 0; w < NWAVE; ++w) if (w < wave) wb += s_i[w][pickT];
    int o = wb + (pre - nt);
#pragma unroll
    for (int k = 0; k < PER; ++k) if (v[k] > tf) s_act[o++] = v[k];
    nact = CT[pickT];
    __syncthreads();
  } else {
    // ---- fallback: register-phase Michelot from the full-set start ----
    tau  = (S - Z_LVL) / (float)N_COLS;
    prev = N_COLS;
    for (int iter = 0; iter < 32; ++iter) {
      const int p = (iter + 1) & 1;
      float ps = 0.f;
      int   pc = 0;
#pragma unroll
      for (int k = 0; k < PER; ++k) {
        bool a = v[k] > tau;
        unsigned long long m = __ballot(a);
        pc += (int)__popcll(m);
        ps += a ? v[k] : 0.f;
      }
      ps = wave_sum_f(ps);
      if (lane == 0) { s_sum2[p][wave] = ps; s_cnt2[p][wave] = pc; }
      __syncthreads();
      float Sv = 0.f; int C = 0;
#pragma unroll
      for (int w = 0; w < NWAVE; ++w) { Sv += s_sum2[p][w]; C += s_cnt2[p][w]; }
      tau = (Sv - Z_LVL) / (float)C;
      if (C == prev) break;
      prev = C;
      if (C <= CAP) {
        int nt = 0;
#pragma unroll
        for (int k = 0; k < PER; ++k) nt += (v[k] > tau) ? 1 : 0;
        int pre = nt;
#pragma unroll
        for (int off = 1; off < 64; off <<= 1) {
          int t = __shfl_up(pre, off, 64);
          if (lane >= off) pre += t;
        }
        if (lane == 63) s_wtot[wave] = pre;
        const int my = pre - nt;
        __syncthreads();
        int wb = 0, ntot = 0;
#pragma unroll
        for (int w = 0; w < NWAVE; ++w) { if (w < wave) wb += s_wtot[w]; ntot += s_wtot[w]; }
        int o = wb + my;
#pragma unroll
        for (int k = 0; k < PER; ++k) if (v[k] > tau) s_act[o++] = v[k];
        nact = ntot;
        __syncthreads();
        break;
      }
    }
  }

  // ---- solve on compacted actives ----
  if (nact >= 0) {
    if (nact <= 64) {
      // single-wave solve: no barriers inside the iteration
      if (wave == 0) {
        const bool valid = lane < nact;
        const float a = valid ? s_act[lane] : 0.f;
        for (int it = 0; it < 64; ++it) {
          bool g = valid && (a > tau);
          int  C = (int)__popcll(__ballot(g));
          float s = wave_bcast_sum_f(g ? a : 0.f);
          tau = (s - Z_LVL) / (float)C;
          if (C == prev) break;
          prev = C;
        }
        if (lane == 0) s_tau = tau;
      }
      __syncthreads();
      tau = s_tau;
    } else {
      for (int it2 = 0; it2 < 64; ++it2) {
        const int p = it2 & 1;
        float ps = 0.f;
        int   pc = 0;
        for (int i = tid; i < nact; i += BLOCK) {
          float a = s_act[i];
          bool g = a > tau;
          ps += g ? a : 0.f;
          pc += g ? 1 : 0;
        }
        ps = wave_sum_f(ps);
        pc = wave_sum_i(pc);
        if (lane == 0) { s_sum2[p][wave] = ps; s_cnt2[p][wave] = pc; }
        __syncthreads();
        float Sv = 0.f; int C = 0;
#pragma unroll
        for (int w = 0; w < NWAVE; ++w) { Sv += s_sum2[p][w]; C += s_cnt2[p][w]; }
        tau = (Sv - Z_LVL) / (float)C;
        if (C == prev) break;
        prev = C;
      }
    }
  }

  // ---- write wp / wc (coalesced float4, nontemporal) ----
  f32x4* __restrict__ wpo = reinterpret_cast<f32x4*>(wp + base);
  f32x4* __restrict__ wco = reinterpret_cast<f32x4*>(wc + base);
#pragma unroll
  for (int k = 0; k < V4_PER; ++k) {
    f32x4 a = { v[4*k+0], v[4*k+1], v[4*k+2], v[4*k+3] };
    f32x4 pv, cv;
    pv.x = fmaxf(a.x - tau, 0.f);  cv.x = a.x - pv.x;
    pv.y = fmaxf(a.y - tau, 0.f);  cv.y = a.y - pv.y;
    pv.z = fmaxf(a.z - tau, 0.f);  cv.z = a.z - pv.z;
    pv.w = fmaxf(a.w - tau, 0.f);  cv.w = a.w - pv.w;
    __builtin_nontemporal_store(pv, &wpo[tid + k * BLOCK]);
    __builtin_nontemporal_store(cv, &wco[tid + k * BLOCK]);
  }
}

extern "C" void kernel_launch(void* const* d_in, const int* in_sizes, int n_in,
                              void* d_out, int out_size, void* d_ws, size_t ws_size,
                              hipStream_t stream) {
  const float* x = (const float*)d_in[0];
  const int rows = in_sizes[0] / N_COLS;

  float* wp = (float*)d_out;
  float* wc = wp + (size_t)rows * N_COLS;

  simplex_proj_kernel<<<rows, BLOCK, 0, stream>>>(x, wp, wc);
}